// Round 2
// baseline (64.052 us; speedup 1.0000x reference)
//
#include <hip/hip_runtime.h>

// PlasticLinear: B=128, IN=512, OUT=512 (f32)
//   out[b,o]      = sum_i input[b,i] * (weight[o,i] + scale[o,i]*hebb[b,o,i])
//   hebb_new[boi] = hebb + lr[o,i]*out[b,o]*(input[b,i] - out[b,o]*hebb)   (pre-bias out)
//   out[b,o]     += bias[o]
//
// One 64-lane wave per (b,o) row; row held in registers (2x float4/lane);
// shfl_xor butterfly reduce; hebb streamed exactly once each way.
// R2: nontemporal loads/stores on the streaming hebb/hebb_new paths to keep
// the reused small tensors (weight/pscale/plr) resident in L2.

static constexpr int Bsz = 128;
static constexpr int IN  = 512;
static constexpr int OUT = 512;

__device__ __forceinline__ float4 nt_load4(const float* p) {
    float4 v;
    v.x = __builtin_nontemporal_load(p + 0);
    v.y = __builtin_nontemporal_load(p + 1);
    v.z = __builtin_nontemporal_load(p + 2);
    v.w = __builtin_nontemporal_load(p + 3);
    return v;
}
__device__ __forceinline__ void nt_store4(float* p, float4 v) {
    __builtin_nontemporal_store(v.x, p + 0);
    __builtin_nontemporal_store(v.y, p + 1);
    __builtin_nontemporal_store(v.z, p + 2);
    __builtin_nontemporal_store(v.w, p + 3);
}

__global__ __launch_bounds__(256) void PlasticLinear_81879256531091_kernel(
    const float* __restrict__ input,    // (B, IN)
    const float* __restrict__ hebb,     // (B, OUT, IN)
    const float* __restrict__ weight,   // (OUT, IN)
    const float* __restrict__ pscale,   // (OUT, IN)
    const float* __restrict__ plr,      // (OUT, IN)
    const float* __restrict__ bias,     // (OUT,)
    float* __restrict__ out_vec,        // (B, OUT)
    float* __restrict__ hebb_new)       // (B, OUT, IN)
{
    const int wid  = (int)((blockIdx.x * blockDim.x + threadIdx.x) >> 6); // global wave = (b,o)
    const int lane = (int)(threadIdx.x & 63);
    const int b = wid >> 9;            // wid / OUT
    const int o = wid & (OUT - 1);     // wid % OUT

    const size_t hbase = (size_t)wid * IN;   // hebb row base (contiguous in (b,o))
    const int    wbase = o * IN;
    const int    ibase = b * IN;
    const int    i0 = lane * 4;        // first float4 sweep: elems [0,256)
    const int    i1 = 256 + lane * 4;  // second sweep: elems [256,512)

    const float4 h0 = nt_load4(hebb + hbase + i0);
    const float4 h1 = nt_load4(hebb + hbase + i1);
    const float4 w0 = *reinterpret_cast<const float4*>(weight + wbase + i0);
    const float4 w1 = *reinterpret_cast<const float4*>(weight + wbase + i1);
    const float4 s0 = *reinterpret_cast<const float4*>(pscale + wbase + i0);
    const float4 s1 = *reinterpret_cast<const float4*>(pscale + wbase + i1);
    const float4 x0 = *reinterpret_cast<const float4*>(input  + ibase + i0);
    const float4 x1 = *reinterpret_cast<const float4*>(input  + ibase + i1);

    // partial dot: input * (weight + scale*hebb)
    float p = 0.0f;
    p = fmaf(x0.x, fmaf(s0.x, h0.x, w0.x), p);
    p = fmaf(x0.y, fmaf(s0.y, h0.y, w0.y), p);
    p = fmaf(x0.z, fmaf(s0.z, h0.z, w0.z), p);
    p = fmaf(x0.w, fmaf(s0.w, h0.w, w0.w), p);
    p = fmaf(x1.x, fmaf(s1.x, h1.x, w1.x), p);
    p = fmaf(x1.y, fmaf(s1.y, h1.y, w1.y), p);
    p = fmaf(x1.z, fmaf(s1.z, h1.z, w1.z), p);
    p = fmaf(x1.w, fmaf(s1.w, h1.w, w1.w), p);

    // 64-lane butterfly reduction -> every lane holds out[b,o] (pre-bias)
    #pragma unroll
    for (int off = 32; off >= 1; off >>= 1)
        p += __shfl_xor(p, off, 64);

    const float4 l0 = *reinterpret_cast<const float4*>(plr + wbase + i0);
    const float4 l1 = *reinterpret_cast<const float4*>(plr + wbase + i1);

    // hebb_new = hebb + lr*p*(input - p*hebb)
    float4 n0, n1;
    n0.x = fmaf(l0.x * p, fmaf(-p, h0.x, x0.x), h0.x);
    n0.y = fmaf(l0.y * p, fmaf(-p, h0.y, x0.y), h0.y);
    n0.z = fmaf(l0.z * p, fmaf(-p, h0.z, x0.z), h0.z);
    n0.w = fmaf(l0.w * p, fmaf(-p, h0.w, x0.w), h0.w);
    n1.x = fmaf(l1.x * p, fmaf(-p, h1.x, x1.x), h1.x);
    n1.y = fmaf(l1.y * p, fmaf(-p, h1.y, x1.y), h1.y);
    n1.z = fmaf(l1.z * p, fmaf(-p, h1.z, x1.z), h1.z);
    n1.w = fmaf(l1.w * p, fmaf(-p, h1.w, x1.w), h1.w);

    nt_store4(hebb_new + hbase + i0, n0);
    nt_store4(hebb_new + hbase + i1, n1);

    if (lane == 0) out_vec[wid] = p + bias[o];
}

extern "C" void kernel_launch(void* const* d_in, const int* in_sizes, int n_in,
                              void* d_out, int out_size, void* d_ws, size_t ws_size,
                              hipStream_t stream) {
    const float* input  = (const float*)d_in[0];
    const float* hebb   = (const float*)d_in[1];
    const float* weight = (const float*)d_in[2];
    const float* pscale = (const float*)d_in[3];
    const float* plr    = (const float*)d_in[4];
    const float* bias   = (const float*)d_in[5];

    float* out_vec  = (float*)d_out;                        // 128*512 f32
    float* hebb_new = (float*)d_out + (size_t)Bsz * OUT;    // 128*512*512 f32

    const int total_waves     = Bsz * OUT;   // 65536 (b,o) rows
    const int waves_per_block = 4;           // 256 threads/block
    dim3 grid(total_waves / waves_per_block);
    dim3 block(256);
    PlasticLinear_81879256531091_kernel<<<grid, block, 0, stream>>>(
        input, hebb, weight, pscale, plr, bias, out_vec, hebb_new);
}

// Round 3
// 43.916 us; speedup vs baseline: 1.4585x; 1.4585x over previous
//
#include <hip/hip_runtime.h>

// PlasticLinear: B=128, IN=512, OUT=512 (f32)
//   out[b,o]      = sum_i input[b,i] * (weight[o,i] + scale[o,i]*hebb[b,o,i])
//   hebb_new[boi] = hebb + lr[o,i]*out[b,o]*(input[b,i] - out[b,o]*hebb)   (pre-bias out)
//   out[b,o]     += bias[o]
//
// One 64-lane wave per (b,o) row; row held in registers (2x float4/lane);
// shfl_xor butterfly reduce; hebb streamed exactly once each way.
// R3: CACHED loads (hebb is ~50-100% Infinity-Cache-resident across replays —
// R2 proved nt loads forfeit that, −40%), but NONTEMPORAL stores for hebb_new
// (write stream has no reuse; keeping it out of L3 preserves hebb residency).

static constexpr int Bsz = 128;
static constexpr int IN  = 512;
static constexpr int OUT = 512;

__device__ __forceinline__ void nt_store4(float* p, float4 v) {
    __builtin_nontemporal_store(v.x, p + 0);
    __builtin_nontemporal_store(v.y, p + 1);
    __builtin_nontemporal_store(v.z, p + 2);
    __builtin_nontemporal_store(v.w, p + 3);
}

__global__ __launch_bounds__(256) void PlasticLinear_81879256531091_kernel(
    const float* __restrict__ input,    // (B, IN)
    const float* __restrict__ hebb,     // (B, OUT, IN)
    const float* __restrict__ weight,   // (OUT, IN)
    const float* __restrict__ pscale,   // (OUT, IN)
    const float* __restrict__ plr,      // (OUT, IN)
    const float* __restrict__ bias,     // (OUT,)
    float* __restrict__ out_vec,        // (B, OUT)
    float* __restrict__ hebb_new)       // (B, OUT, IN)
{
    const int wid  = (int)((blockIdx.x * blockDim.x + threadIdx.x) >> 6); // global wave = (b,o)
    const int lane = (int)(threadIdx.x & 63);
    const int b = wid >> 9;            // wid / OUT
    const int o = wid & (OUT - 1);     // wid % OUT

    const size_t hbase = (size_t)wid * IN;   // hebb row base (contiguous in (b,o))
    const int    wbase = o * IN;
    const int    ibase = b * IN;
    const int    i0 = lane * 4;        // first float4 sweep: elems [0,256)
    const int    i1 = 256 + lane * 4;  // second sweep: elems [256,512)

    const float4 h0 = *reinterpret_cast<const float4*>(hebb   + hbase + i0);
    const float4 h1 = *reinterpret_cast<const float4*>(hebb   + hbase + i1);
    const float4 w0 = *reinterpret_cast<const float4*>(weight + wbase + i0);
    const float4 w1 = *reinterpret_cast<const float4*>(weight + wbase + i1);
    const float4 s0 = *reinterpret_cast<const float4*>(pscale + wbase + i0);
    const float4 s1 = *reinterpret_cast<const float4*>(pscale + wbase + i1);
    const float4 x0 = *reinterpret_cast<const float4*>(input  + ibase + i0);
    const float4 x1 = *reinterpret_cast<const float4*>(input  + ibase + i1);

    // partial dot: input * (weight + scale*hebb)
    float p = 0.0f;
    p = fmaf(x0.x, fmaf(s0.x, h0.x, w0.x), p);
    p = fmaf(x0.y, fmaf(s0.y, h0.y, w0.y), p);
    p = fmaf(x0.z, fmaf(s0.z, h0.z, w0.z), p);
    p = fmaf(x0.w, fmaf(s0.w, h0.w, w0.w), p);
    p = fmaf(x1.x, fmaf(s1.x, h1.x, w1.x), p);
    p = fmaf(x1.y, fmaf(s1.y, h1.y, w1.y), p);
    p = fmaf(x1.z, fmaf(s1.z, h1.z, w1.z), p);
    p = fmaf(x1.w, fmaf(s1.w, h1.w, w1.w), p);

    // 64-lane butterfly reduction -> every lane holds out[b,o] (pre-bias)
    #pragma unroll
    for (int off = 32; off >= 1; off >>= 1)
        p += __shfl_xor(p, off, 64);

    const float4 l0 = *reinterpret_cast<const float4*>(plr + wbase + i0);
    const float4 l1 = *reinterpret_cast<const float4*>(plr + wbase + i1);

    // hebb_new = hebb + lr*p*(input - p*hebb)
    float4 n0, n1;
    n0.x = fmaf(l0.x * p, fmaf(-p, h0.x, x0.x), h0.x);
    n0.y = fmaf(l0.y * p, fmaf(-p, h0.y, x0.y), h0.y);
    n0.z = fmaf(l0.z * p, fmaf(-p, h0.z, x0.z), h0.z);
    n0.w = fmaf(l0.w * p, fmaf(-p, h0.w, x0.w), h0.w);
    n1.x = fmaf(l1.x * p, fmaf(-p, h1.x, x1.x), h1.x);
    n1.y = fmaf(l1.y * p, fmaf(-p, h1.y, x1.y), h1.y);
    n1.z = fmaf(l1.z * p, fmaf(-p, h1.z, x1.z), h1.z);
    n1.w = fmaf(l1.w * p, fmaf(-p, h1.w, x1.w), h1.w);

    nt_store4(hebb_new + hbase + i0, n0);
    nt_store4(hebb_new + hbase + i1, n1);

    if (lane == 0) out_vec[wid] = p + bias[o];
}

extern "C" void kernel_launch(void* const* d_in, const int* in_sizes, int n_in,
                              void* d_out, int out_size, void* d_ws, size_t ws_size,
                              hipStream_t stream) {
    const float* input  = (const float*)d_in[0];
    const float* hebb   = (const float*)d_in[1];
    const float* weight = (const float*)d_in[2];
    const float* pscale = (const float*)d_in[3];
    const float* plr    = (const float*)d_in[4];
    const float* bias   = (const float*)d_in[5];

    float* out_vec  = (float*)d_out;                        // 128*512 f32
    float* hebb_new = (float*)d_out + (size_t)Bsz * OUT;    // 128*512*512 f32

    const int total_waves     = Bsz * OUT;   // 65536 (b,o) rows
    const int waves_per_block = 4;           // 256 threads/block
    dim3 grid(total_waves / waves_per_block);
    dim3 block(256);
    PlasticLinear_81879256531091_kernel<<<grid, block, 0, stream>>>(
        input, hebb, weight, pscale, plr, bias, out_vec, hebb_new);
}

// Round 6
// 43.708 us; speedup vs baseline: 1.4655x; 1.0048x over previous
//
#include <hip/hip_runtime.h>

// PlasticLinear: B=128, IN=512, OUT=512 (f32)
//   out[b,o]      = sum_i input[b,i] * (weight[o,i] + scale[o,i]*hebb[b,o,i])
//   hebb_new[boi] = hebb + lr[o,i]*out[b,o]*(input[b,i] - out[b,o]*hebb)   (pre-bias out)
//   out[b,o]     += bias[o]
//
// FINAL (= R3, best passing at 43.9 us = ~98% of the 6.3 TB/s copy ceiling):
// One 64-lane wave per (b,o) row; row held in registers (2x float4/lane);
// shfl_xor butterfly reduce; hebb streamed exactly once each way.
// - CACHED loads: hebb is partially Infinity-Cache-resident across replays
//   (R2 proved nt loads forfeit that: -40%).
// - builtin-nontemporal stores on hebb_new (+4% vs cached stores, R3).
// - Full cache-bypass stores (sc0 sc1 nt) are INCORRECT here: the harness's
//   memset leaves dirty lines in L2/MALL that later evict over bypassed
//   writes (R5 failed validation). Do not re-attempt.

static constexpr int Bsz = 128;
static constexpr int IN  = 512;
static constexpr int OUT = 512;

__device__ __forceinline__ void nt_store4(float* p, float4 v) {
    __builtin_nontemporal_store(v.x, p + 0);
    __builtin_nontemporal_store(v.y, p + 1);
    __builtin_nontemporal_store(v.z, p + 2);
    __builtin_nontemporal_store(v.w, p + 3);
}

__global__ __launch_bounds__(256) void PlasticLinear_81879256531091_kernel(
    const float* __restrict__ input,    // (B, IN)
    const float* __restrict__ hebb,     // (B, OUT, IN)
    const float* __restrict__ weight,   // (OUT, IN)
    const float* __restrict__ pscale,   // (OUT, IN)
    const float* __restrict__ plr,      // (OUT, IN)
    const float* __restrict__ bias,     // (OUT,)
    float* __restrict__ out_vec,        // (B, OUT)
    float* __restrict__ hebb_new)       // (B, OUT, IN)
{
    const int wid  = (int)((blockIdx.x * blockDim.x + threadIdx.x) >> 6); // global wave = (b,o)
    const int lane = (int)(threadIdx.x & 63);
    const int b = wid >> 9;            // wid / OUT
    const int o = wid & (OUT - 1);     // wid % OUT

    const size_t hbase = (size_t)wid * IN;   // hebb row base (contiguous in (b,o))
    const int    wbase = o * IN;
    const int    ibase = b * IN;
    const int    i0 = lane * 4;        // first float4 sweep: elems [0,256)
    const int    i1 = 256 + lane * 4;  // second sweep: elems [256,512)

    const float4 h0 = *reinterpret_cast<const float4*>(hebb   + hbase + i0);
    const float4 h1 = *reinterpret_cast<const float4*>(hebb   + hbase + i1);
    const float4 w0 = *reinterpret_cast<const float4*>(weight + wbase + i0);
    const float4 w1 = *reinterpret_cast<const float4*>(weight + wbase + i1);
    const float4 s0 = *reinterpret_cast<const float4*>(pscale + wbase + i0);
    const float4 s1 = *reinterpret_cast<const float4*>(pscale + wbase + i1);
    const float4 x0 = *reinterpret_cast<const float4*>(input  + ibase + i0);
    const float4 x1 = *reinterpret_cast<const float4*>(input  + ibase + i1);

    // partial dot: input * (weight + scale*hebb)
    float p = 0.0f;
    p = fmaf(x0.x, fmaf(s0.x, h0.x, w0.x), p);
    p = fmaf(x0.y, fmaf(s0.y, h0.y, w0.y), p);
    p = fmaf(x0.z, fmaf(s0.z, h0.z, w0.z), p);
    p = fmaf(x0.w, fmaf(s0.w, h0.w, w0.w), p);
    p = fmaf(x1.x, fmaf(s1.x, h1.x, w1.x), p);
    p = fmaf(x1.y, fmaf(s1.y, h1.y, w1.y), p);
    p = fmaf(x1.z, fmaf(s1.z, h1.z, w1.z), p);
    p = fmaf(x1.w, fmaf(s1.w, h1.w, w1.w), p);

    // 64-lane butterfly reduction -> every lane holds out[b,o] (pre-bias)
    #pragma unroll
    for (int off = 32; off >= 1; off >>= 1)
        p += __shfl_xor(p, off, 64);

    const float4 l0 = *reinterpret_cast<const float4*>(plr + wbase + i0);
    const float4 l1 = *reinterpret_cast<const float4*>(plr + wbase + i1);

    // hebb_new = hebb + lr*p*(input - p*hebb)
    float4 n0, n1;
    n0.x = fmaf(l0.x * p, fmaf(-p, h0.x, x0.x), h0.x);
    n0.y = fmaf(l0.y * p, fmaf(-p, h0.y, x0.y), h0.y);
    n0.z = fmaf(l0.z * p, fmaf(-p, h0.z, x0.z), h0.z);
    n0.w = fmaf(l0.w * p, fmaf(-p, h0.w, x0.w), h0.w);
    n1.x = fmaf(l1.x * p, fmaf(-p, h1.x, x1.x), h1.x);
    n1.y = fmaf(l1.y * p, fmaf(-p, h1.y, x1.y), h1.y);
    n1.z = fmaf(l1.z * p, fmaf(-p, h1.z, x1.z), h1.z);
    n1.w = fmaf(l1.w * p, fmaf(-p, h1.w, x1.w), h1.w);

    nt_store4(hebb_new + hbase + i0, n0);
    nt_store4(hebb_new + hbase + i1, n1);

    if (lane == 0) out_vec[wid] = p + bias[o];
}

extern "C" void kernel_launch(void* const* d_in, const int* in_sizes, int n_in,
                              void* d_out, int out_size, void* d_ws, size_t ws_size,
                              hipStream_t stream) {
    const float* input  = (const float*)d_in[0];
    const float* hebb   = (const float*)d_in[1];
    const float* weight = (const float*)d_in[2];
    const float* pscale = (const float*)d_in[3];
    const float* plr    = (const float*)d_in[4];
    const float* bias   = (const float*)d_in[5];

    float* out_vec  = (float*)d_out;                        // 128*512 f32
    float* hebb_new = (float*)d_out + (size_t)Bsz * OUT;    // 128*512*512 f32

    const int total_waves     = Bsz * OUT;   // 65536 (b,o) rows
    const int waves_per_block = 4;           // 256 threads/block
    dim3 grid(total_waves / waves_per_block);
    dim3 block(256);
    PlasticLinear_81879256531091_kernel<<<grid, block, 0, stream>>>(
        input, hebb, weight, pscale, plr, bias, out_vec, hebb_new);
}